// Round 1
// 271.051 us; speedup vs baseline: 1.0459x; 1.0459x over previous
//
#include <hip/hip_runtime.h>

#define N_   64
#define C_   512
#define HW_  1024
#define SC_  64              // spatial chunk per fused block
#define NSC_ (HW_ / SC_)     // 16 chunks -> grid = 64*16 = 1024 blocks

// ---------------------------------------------------------------------------
// K1: gap[n*C+c] = mean over 1024 contiguous spatial elements.
// One wave per row, 4 rows per block, float4 loads. Normal (caching) loads:
// intentionally warms L3 with x for the fused pass.
// ---------------------------------------------------------------------------
__global__ __launch_bounds__(256) void gap_kernel(const float* __restrict__ x,
                                                  float* __restrict__ gap) {
    int wave = threadIdx.x >> 6;
    int lane = threadIdx.x & 63;
    int row  = blockIdx.x * 4 + wave;                 // row = n*C + c
    const float4* xr = (const float4*)(x + (size_t)row * HW_);
    float s = 0.f;
    #pragma unroll
    for (int j = 0; j < 4; ++j) {
        float4 v = xr[lane + j * 64];
        s += v.x + v.y + v.z + v.w;
    }
    #pragma unroll
    for (int off = 32; off > 0; off >>= 1) s += __shfl_down(s, off, 64);
    if (lane == 0) gap[row] = s * (1.0f / 1024.0f);
}

// ---------------------------------------------------------------------------
// K2: fused qk + moments + apply.
// Block = (n, s-chunk of 64). 256 threads = 4 waves; lane owns one s,
// wave wv strides channels c = wv + 4j.
// Phase A: q,k,alpha recomputed in-block from gap (redundant, tiny).
// Phase B: mom_t[s] = sum_c k_c^t x[c,s]  (normal loads -> cache for C).
// Phase C: out[d,s] = x[d,s] * Horner_q_d(mom[.][s])  (NT loads/stores,
//          re-reads phase-B's 128 KiB slice from L2/L3).
// ---------------------------------------------------------------------------
__global__ __launch_bounds__(256) void fused_kernel(const float* __restrict__ x,
    const float* __restrict__ gap,
    const float* __restrict__ wq, const float* __restrict__ bq,
    const float* __restrict__ wk, const float* __restrict__ bk,
    float* __restrict__ out) {
    __shared__ float g[C_ + 2];
    __shared__ float qs[C_], ks[C_];
    __shared__ float part[4][12];
    __shared__ float mpart[4][7][SC_];
    __shared__ float mfin[7][SC_];
    __shared__ float invf[8];
    __shared__ float alpha_s;

    int n     = blockIdx.x >> 4;          // / NSC_
    int chunk = blockIdx.x & (NSC_ - 1);
    int tid   = threadIdx.x;
    int lane  = tid & 63;
    int wv    = tid >> 6;

    if (tid == 0) {
        g[0] = 0.f; g[C_ + 1] = 0.f;
        invf[0] = 1.f;        invf[1] = 1.f;         invf[2] = 0.5f;
        invf[3] = 1.f / 6.f;  invf[4] = 1.f / 24.f;  invf[5] = 1.f / 120.f;
        invf[6] = 1.f / 720.f;
    }
    g[1 + tid]       = gap[n * C_ + tid];
    g[1 + tid + 256] = gap[n * C_ + tid + 256];
    __syncthreads();

    // ---- phase A: q, k, power sums, alpha = 1/S ----
    float w0 = wq[0], w1 = wq[1], w2 = wq[2], b0 = bq[0];
    float u0 = wk[0], u1 = wk[1], u2 = wk[2], c0 = bk[0];

    float sq[6] = {0, 0, 0, 0, 0, 0};
    float sk[6] = {0, 0, 0, 0, 0, 0};
    #pragma unroll
    for (int j = 0; j < 2; ++j) {
        int c = tid + j * 256;
        float qv = fmaxf(0.f, w0 * g[c] + w1 * g[c + 1] + w2 * g[c + 2] + b0);
        float kv = fmaxf(0.f, u0 * g[c] + u1 * g[c + 1] + u2 * g[c + 2] + c0);
        qs[c] = qv; ks[c] = kv;
        float pq = qv, pk = kv;
        #pragma unroll
        for (int t = 0; t < 6; ++t) { sq[t] += pq; pq *= qv; sk[t] += pk; pk *= kv; }
    }
    {
        float vals[12];
        #pragma unroll
        for (int t = 0; t < 6; ++t) { vals[t] = sq[t]; vals[6 + t] = sk[t]; }
        #pragma unroll
        for (int j = 0; j < 12; ++j) {
            float v = vals[j];
            #pragma unroll
            for (int off = 32; off > 0; off >>= 1) v += __shfl_down(v, off, 64);
            if (lane == 0) part[wv][j] = v;
        }
    }
    __syncthreads();
    if (tid == 0) {
        const float ifct[6] = {1.f, 0.5f, 1.f / 6.f, 1.f / 24.f,
                               1.f / 120.f, 1.f / 720.f};
        float S = (float)C_ * (float)C_;
        #pragma unroll
        for (int t = 0; t < 6; ++t) {
            float tq = 0.f, tk = 0.f;
            #pragma unroll
            for (int w = 0; w < 4; ++w) { tq += part[w][t]; tk += part[w][6 + t]; }
            S += tq * tk * ifct[t];
        }
        alpha_s = 1.0f / S;
    }
    // alpha_s visibility is covered by the barrier after phase B.

    // ---- phase B: moments. s = chunk*64 + lane, c = wv + 4j ----
    int s0 = chunk * SC_;
    const float* xb = x + ((size_t)n * C_ + wv) * HW_ + s0 + lane;
    float m0 = 0, m1 = 0, m2 = 0, m3 = 0, m4 = 0, m5 = 0, m6 = 0;
    #pragma unroll 8
    for (int j = 0; j < C_ / 4; ++j) {
        float xv = xb[(size_t)(4 * j) * HW_];
        float kc = ks[wv + 4 * j];
        float p = xv;
        m0 += p; p *= kc;
        m1 += p; p *= kc;
        m2 += p; p *= kc;
        m3 += p; p *= kc;
        m4 += p; p *= kc;
        m5 += p; p *= kc;
        m6 += p;
    }
    mpart[wv][0][lane] = m0; mpart[wv][1][lane] = m1; mpart[wv][2][lane] = m2;
    mpart[wv][3][lane] = m3; mpart[wv][4][lane] = m4; mpart[wv][5][lane] = m5;
    mpart[wv][6][lane] = m6;
    __syncthreads();

    if (tid < 7 * SC_) {                  // 448 threads: (t, l)
        int t = tid >> 6, l = tid & 63;
        float v = mpart[0][t][l] + mpart[1][t][l] + mpart[2][t][l]
                + mpart[3][t][l];
        mfin[t][l] = v * alpha_s * invf[t];
    }
    __syncthreads();

    // ---- phase C: apply. d = wv + 4j, same s per lane ----
    float a0 = mfin[0][lane], a1 = mfin[1][lane], a2 = mfin[2][lane],
          a3 = mfin[3][lane], a4 = mfin[4][lane], a5 = mfin[5][lane],
          a6 = mfin[6][lane];
    const float* xr = x   + ((size_t)n * C_ + wv) * HW_ + s0 + lane;
    float*       og = out + ((size_t)n * C_ + wv) * HW_ + s0 + lane;
    #pragma unroll 8
    for (int j = 0; j < C_ / 4; ++j) {
        float q   = qs[wv + 4 * j];
        float att = fmaf(q, a6, a5);
        att = fmaf(q, att, a4);
        att = fmaf(q, att, a3);
        att = fmaf(q, att, a2);
        att = fmaf(q, att, a1);
        att = fmaf(q, att, a0);
        float xv = __builtin_nontemporal_load(xr + (size_t)(4 * j) * HW_);
        __builtin_nontemporal_store(xv * att, og + (size_t)(4 * j) * HW_);
    }
}

// ---------------------------------------------------------------------------
extern "C" void kernel_launch(void* const* d_in, const int* in_sizes, int n_in,
                              void* d_out, int out_size, void* d_ws, size_t ws_size,
                              hipStream_t stream) {
    const float* x  = (const float*)d_in[0];
    const float* wq = (const float*)d_in[1];
    const float* bq = (const float*)d_in[2];
    const float* wk = (const float*)d_in[3];
    const float* bk = (const float*)d_in[4];
    float* out = (float*)d_out;

    float* gap = (float*)d_ws;            // N*C = 32768 floats

    gap_kernel  <<<dim3(N_ * C_ / 4), dim3(256), 0, stream>>>(x, gap);
    fused_kernel<<<dim3(N_ * NSC_),   dim3(256), 0, stream>>>(x, gap, wq, bq,
                                                              wk, bk, out);
}

// Round 8
// 269.789 us; speedup vs baseline: 1.0508x; 1.0047x over previous
//
#include <hip/hip_runtime.h>

#define N_   64
#define C_   512
#define HW_  1024
#define SC_  64              // spatial chunk per fused block
#define NSC_ (HW_ / SC_)     // 16 chunks -> grid = 64*16 = 1024 blocks

typedef float f4v __attribute__((ext_vector_type(4)));

// ---------------------------------------------------------------------------
// K1: gap[n*C+c] = mean over 1024 contiguous spatial elements.
// ---------------------------------------------------------------------------
__global__ __launch_bounds__(256) void gap_kernel(const float* __restrict__ x,
                                                  float* __restrict__ gap) {
    int wave = threadIdx.x >> 6;
    int lane = threadIdx.x & 63;
    int row  = blockIdx.x * 4 + wave;                 // row = n*C + c
    const float4* xr = (const float4*)(x + (size_t)row * HW_);
    float s = 0.f;
    #pragma unroll
    for (int j = 0; j < 4; ++j) {
        float4 v = xr[lane + j * 64];
        s += v.x + v.y + v.z + v.w;
    }
    #pragma unroll
    for (int off = 32; off > 0; off >>= 1) s += __shfl_down(s, off, 64);
    if (lane == 0) gap[row] = s * (1.0f / 1024.0f);
}

// ---------------------------------------------------------------------------
// K2: fused qk + moments + apply. Block = (n, s-chunk of 64), 256 threads.
// BUGFIX vs rounds 1-7: the mfin reduce previously ran under
// `if (tid < 448)` with a 256-thread block -> t=4..6 coefficients were
// NEVER WRITTEN (stale LDS). Round-1's "pass" was luck (stale ~zero);
// later layout changes made the staleness nonzero -> build-dependent
// failures. Now a strided loop covers all 7*64 (t,l) pairs.
// ---------------------------------------------------------------------------
__global__ __launch_bounds__(256) void fused_kernel(const float* __restrict__ x,
    const float* __restrict__ gap,
    const float* __restrict__ wq, const float* __restrict__ bq,
    const float* __restrict__ wk, const float* __restrict__ bk,
    float* __restrict__ out) {
    __shared__ float g[C_ + 2];
    __shared__ float qs[C_], ks[C_];
    __shared__ float red[4][12];
    __shared__ alignas(16) float mpart[4][7][SC_];
    __shared__ alignas(16) float mfin[7][SC_];
    __shared__ float invf[8];
    __shared__ float alpha_s;

    int n     = blockIdx.x >> 4;          // / NSC_
    int chunk = blockIdx.x & (NSC_ - 1);
    int tid   = threadIdx.x;
    int lane  = tid & 63;
    int wv    = tid >> 6;
    int s0    = chunk * SC_;

    if (tid == 0) {
        g[0] = 0.f; g[C_ + 1] = 0.f;
        invf[0] = 1.f;        invf[1] = 1.f;         invf[2] = 0.5f;
        invf[3] = 1.f / 6.f;  invf[4] = 1.f / 24.f;  invf[5] = 1.f / 120.f;
        invf[6] = 1.f / 720.f;
    }
    g[1 + tid]       = gap[n * C_ + tid];
    g[1 + tid + 256] = gap[n * C_ + tid + 256];
    __syncthreads();

    // ---- phase A: q, k, power sums, alpha = 1/S ----
    float w0 = wq[0], w1 = wq[1], w2 = wq[2], b0 = bq[0];
    float u0 = wk[0], u1 = wk[1], u2 = wk[2], c0 = bk[0];

    float sq[6] = {0, 0, 0, 0, 0, 0};
    float sk[6] = {0, 0, 0, 0, 0, 0};
    #pragma unroll
    for (int j = 0; j < 2; ++j) {
        int c = tid + j * 256;
        float qv = fmaxf(0.f, w0 * g[c] + w1 * g[c + 1] + w2 * g[c + 2] + b0);
        float kv = fmaxf(0.f, u0 * g[c] + u1 * g[c + 1] + u2 * g[c + 2] + c0);
        qs[c] = qv; ks[c] = kv;
        float pq = qv, pk = kv;
        #pragma unroll
        for (int t = 0; t < 6; ++t) { sq[t] += pq; pq *= qv; sk[t] += pk; pk *= kv; }
    }
    {
        float vals[12];
        #pragma unroll
        for (int t = 0; t < 6; ++t) { vals[t] = sq[t]; vals[6 + t] = sk[t]; }
        #pragma unroll
        for (int j = 0; j < 12; ++j) {
            float v = vals[j];
            #pragma unroll
            for (int off = 32; off > 0; off >>= 1) v += __shfl_down(v, off, 64);
            if (lane == 0) red[wv][j] = v;
        }
    }
    __syncthreads();
    if (tid == 0) {
        const float ifct[6] = {1.f, 0.5f, 1.f / 6.f, 1.f / 24.f,
                               1.f / 120.f, 1.f / 720.f};
        float S = (float)C_ * (float)C_;
        #pragma unroll
        for (int t = 0; t < 6; ++t) {
            float tq = 0.f, tk = 0.f;
            #pragma unroll
            for (int w = 0; w < 4; ++w) { tq += red[w][t]; tk += red[w][6 + t]; }
            S += tq * tk * ifct[t];
        }
        alpha_s = 1.0f / S;
    }
    // alpha_s visibility covered by the barrier after phase B.

    // ---- phase B: moments. s = s0 + lane, c = wv + 4j ----
    const float* xb = x + ((size_t)n * C_ + wv) * HW_ + s0 + lane;
    float m0 = 0, m1 = 0, m2 = 0, m3 = 0, m4 = 0, m5 = 0, m6 = 0;
    #pragma unroll 8
    for (int j = 0; j < C_ / 4; ++j) {
        float xv = xb[(size_t)(4 * j) * HW_];
        float kc = ks[wv + 4 * j];
        float p = xv;
        m0 += p; p *= kc;
        m1 += p; p *= kc;
        m2 += p; p *= kc;
        m3 += p; p *= kc;
        m4 += p; p *= kc;
        m5 += p; p *= kc;
        m6 += p;
    }
    mpart[wv][0][lane] = m0; mpart[wv][1][lane] = m1; mpart[wv][2][lane] = m2;
    mpart[wv][3][lane] = m3; mpart[wv][4][lane] = m4; mpart[wv][5][lane] = m5;
    mpart[wv][6][lane] = m6;
    __syncthreads();

    // ---- mfin reduce: ALL 7*64 pairs via strided loop (256 threads) ----
    #pragma unroll
    for (int r = 0; r < 7 * SC_; r += 256) {
        int idx = r + tid;
        if (idx < 7 * SC_) {
            int t = idx >> 6, l = idx & 63;
            float v = mpart[0][t][l] + mpart[1][t][l] + mpart[2][t][l]
                    + mpart[3][t][l];
            mfin[t][l] = v * alpha_s * invf[t];
        }
    }
    __syncthreads();

    // ---- phase C: apply, float4 over s-quads ----
    {
        int sq4 = tid & 15;               // s-quad (4 consecutive s)
        int cg4 = tid >> 4;               // row-group (0..15)
        float4 a0, a1, a2, a3, a4, a5, a6;
        {
            int b = 4 * sq4;
            a0 = make_float4(mfin[0][b], mfin[0][b+1], mfin[0][b+2], mfin[0][b+3]);
            a1 = make_float4(mfin[1][b], mfin[1][b+1], mfin[1][b+2], mfin[1][b+3]);
            a2 = make_float4(mfin[2][b], mfin[2][b+1], mfin[2][b+2], mfin[2][b+3]);
            a3 = make_float4(mfin[3][b], mfin[3][b+1], mfin[3][b+2], mfin[3][b+3]);
            a4 = make_float4(mfin[4][b], mfin[4][b+1], mfin[4][b+2], mfin[4][b+3]);
            a5 = make_float4(mfin[5][b], mfin[5][b+1], mfin[5][b+2], mfin[5][b+3]);
            a6 = make_float4(mfin[6][b], mfin[6][b+1], mfin[6][b+2], mfin[6][b+3]);
        }
        const f4v* xr = (const f4v*)(x   + ((size_t)n * C_ + cg4) * HW_ + s0 + 4 * sq4);
        f4v*       og = (f4v*)(out + ((size_t)n * C_ + cg4) * HW_ + s0 + 4 * sq4);
        #pragma unroll 8
        for (int j = 0; j < 32; ++j) {
            float q = qs[cg4 + 16 * j];
            float4 att;
            att.x = fmaf(q, a6.x, a5.x); att.y = fmaf(q, a6.y, a5.y);
            att.z = fmaf(q, a6.z, a5.z); att.w = fmaf(q, a6.w, a5.w);
            att.x = fmaf(q, att.x, a4.x); att.y = fmaf(q, att.y, a4.y);
            att.z = fmaf(q, att.z, a4.z); att.w = fmaf(q, att.w, a4.w);
            att.x = fmaf(q, att.x, a3.x); att.y = fmaf(q, att.y, a3.y);
            att.z = fmaf(q, att.z, a3.z); att.w = fmaf(q, att.w, a3.w);
            att.x = fmaf(q, att.x, a2.x); att.y = fmaf(q, att.y, a2.y);
            att.z = fmaf(q, att.z, a2.z); att.w = fmaf(q, att.w, a2.w);
            att.x = fmaf(q, att.x, a1.x); att.y = fmaf(q, att.y, a1.y);
            att.z = fmaf(q, att.z, a1.z); att.w = fmaf(q, att.w, a1.w);
            att.x = fmaf(q, att.x, a0.x); att.y = fmaf(q, att.y, a0.y);
            att.z = fmaf(q, att.z, a0.z); att.w = fmaf(q, att.w, a0.w);
            // row stride per j: 16 rows, each HW_/4 f4v wide.
            f4v xv = __builtin_nontemporal_load(xr + (size_t)(16 * j) * (HW_ / 4));
            f4v res;
            res.x = xv.x * att.x; res.y = xv.y * att.y;
            res.z = xv.z * att.z; res.w = xv.w * att.w;
            __builtin_nontemporal_store(res, og + (size_t)(16 * j) * (HW_ / 4));
        }
    }
}

// ---------------------------------------------------------------------------
extern "C" void kernel_launch(void* const* d_in, const int* in_sizes, int n_in,
                              void* d_out, int out_size, void* d_ws, size_t ws_size,
                              hipStream_t stream) {
    const float* x  = (const float*)d_in[0];
    const float* wq = (const float*)d_in[1];
    const float* bq = (const float*)d_in[2];
    const float* wk = (const float*)d_in[3];
    const float* bk = (const float*)d_in[4];
    float* out = (float*)d_out;

    float* gap = (float*)d_ws;            // N*C = 32768 floats

    gap_kernel  <<<dim3(N_ * C_ / 4), dim3(256), 0, stream>>>(x, gap);
    fused_kernel<<<dim3(N_ * NSC_),   dim3(256), 0, stream>>>(x, gap, wq, bq,
                                                              wk, bk, out);
}